// Round 1
// baseline (117.248 us; speedup 1.0000x reference)
//
#include <hip/hip_runtime.h>
#include <math.h>

#define NEGV -1e30f

constexpr int B_  = 16;
constexpr int CL  = 512;
constexpr int QL  = 64;
constexpr int H   = 768;
constexpr int IT  = 32;        // i-tile rows per block in ka
constexpr int DC  = 128;       // d-chunk
constexpr int NCH = H / DC;    // 6
constexpr int OD  = 4 * H;     // 3072 output cols

// ws layout (floats)
constexpr size_t WS_QW     = 0;            // [1024]   qw[b,j]
constexpr size_t WS_ROWMAX = 1024;         // [8192]   max_j s (c_mask applied)
constexpr size_t WS_BATT   = 9216;         // [8192]   b_att
constexpr size_t WS_PART   = 17408;        // [16*32*768] q2c partials
constexpr size_t WS_Q2C    = 410624;       // [12288]  q2c[b,d]

// ---------------- qw[b,j] = q[b,j,:] . w_q + b_q ----------------
__global__ __launch_bounds__(256) void k_qw(const float* __restrict__ q,
                                            const float* __restrict__ w_q,
                                            const float* __restrict__ b_q,
                                            float* __restrict__ qw) {
  int w = threadIdx.x >> 6, lane = threadIdx.x & 63;
  int row = blockIdx.x * 4 + w;                 // 0..1023 = b*QL+j
  const float* qr = q + (size_t)row * H;
  float s = 0.f;
  for (int d = lane; d < H; d += 64) s += qr[d] * w_q[d];
#pragma unroll
  for (int off = 32; off; off >>= 1) s += __shfl_xor(s, off);
  if (lane == 0) qw[row] = s + b_q[0];
}

// ---------------- main kernel: s, softmax_j, c2q, out segs 0/1/2 ----------------
__global__ __launch_bounds__(128) void ka(const float* __restrict__ c,
                                          const float* __restrict__ q,
                                          const float* __restrict__ c_mask,
                                          const float* __restrict__ q_mask,
                                          const float* __restrict__ w_c,
                                          const float* __restrict__ b_c,
                                          const float* __restrict__ w_cq,
                                          const float* __restrict__ b_cq,
                                          const float* __restrict__ qw,
                                          float* __restrict__ rowmax,
                                          float* __restrict__ out) {
  __shared__ float cS[IT * 132];     // chunk of raw c, row-major [i][dd], stride 132
  __shared__ float qB[128 * 68];     // ph1: q transposed [dd][j] (XOR-swizzled); ph3: row-major [64][136]
  __shared__ float sS[IT * 68];      // s tile
  __shared__ float aT[QL * 36];      // a transposed [j][i]
  __shared__ float wS[DC], wqS[DC];  // w_c / w_cq chunks
  __shared__ float cwS[IT], qwS[QL], qmS[QL], cmS[IT];

  const int t  = threadIdx.x;
  const int b  = blockIdx.y;
  const int i0 = blockIdx.x * IT;

  if (t < QL) { qwS[t] = qw[b * QL + t]; qmS[t] = q_mask[b * QL + t]; }
  if (t >= QL && t < QL + IT) { int r = t - QL; cmS[r] = c_mask[b * CL + i0 + r]; }
  const float bcq = b_cq[0], bc = b_c[0];

  const int ig = t >> 4, jg = t & 15;
  const int r0 = ig * 4, c0 = jg * 4;   // this thread's 4 i-rows / 4 j-cols of s

  float acc[4][4] = {};
  float cwp = 0.f;

  const size_t cbase = ((size_t)b * CL + i0) * H;
  const size_t qbase = (size_t)b * QL * H;

  // ---- phase 1: s = (c*w_cq) @ q^T, fused cw = c.w_c ----
  for (int ch = 0; ch < NCH; ++ch) {
    const int d0 = ch * DC;
    __syncthreads();
    wS[t]  = w_c[d0 + t];
    wqS[t] = w_cq[d0 + t];
#pragma unroll
    for (int s = 0; s < 8; ++s) {      // stage c chunk (32x128) as float4
      int f = t + s * 128, i = f >> 5, dd4 = f & 31;
      float4 v = *(const float4*)(c + cbase + (size_t)i * H + d0 + dd4 * 4);
      *(float4*)&cS[i * 132 + dd4 * 4] = v;
    }
#pragma unroll
    for (int s = 0; s < 16; ++s) {     // stage q chunk transposed+swizzled (128x64)
      int f = t + s * 128, j = f >> 5, dd4 = f & 31;
      float4 v = *(const float4*)(q + qbase + (size_t)j * H + d0 + dd4 * 4);
      int js = j ^ ((dd4 & 15) << 2);
      float* p = &qB[dd4 * 4 * 68 + js];
      p[0] = v.x; p[68] = v.y; p[136] = v.z; p[204] = v.w;
    }
    __syncthreads();
    {  // cw partial: 4 threads per row
      int row = t >> 2, kk = (t & 3) * 32;
#pragma unroll
      for (int u = 0; u < 32; ++u) cwp += cS[row * 132 + kk + u] * wS[kk + u];
    }
#pragma unroll 4
    for (int dd4 = 0; dd4 < 32; ++dd4) {
      const int X = (dd4 & 15) << 2;
      float4 wq4 = *(const float4*)&wqS[dd4 * 4];
      float cs[4][4];
#pragma unroll
      for (int r = 0; r < 4; ++r) {
        float4 cv = *(const float4*)&cS[(r0 + r) * 132 + dd4 * 4];
        cs[r][0] = cv.x * wq4.x; cs[r][1] = cv.y * wq4.y;
        cs[r][2] = cv.z * wq4.z; cs[r][3] = cv.w * wq4.w;
      }
      const int qb0 = dd4 * 4 * 68 + (c0 ^ X);
#pragma unroll
      for (int e = 0; e < 4; ++e) {
        float4 qv = *(const float4*)&qB[qb0 + e * 68];
#pragma unroll
        for (int r = 0; r < 4; ++r) {
          acc[r][0] += cs[r][e] * qv.x;
          acc[r][1] += cs[r][e] * qv.y;
          acc[r][2] += cs[r][e] * qv.z;
          acc[r][3] += cs[r][e] * qv.w;
        }
      }
    }
  }
  // cw quad-reduce (lanes 4r..4r+3)
  cwp += __shfl_xor(cwp, 1);
  cwp += __shfl_xor(cwp, 2);
  if ((t & 3) == 0) cwS[t >> 2] = cwp + bc;
  __syncthreads();
  // finalize s into sS
#pragma unroll
  for (int r = 0; r < 4; ++r) {
    float cw = cwS[r0 + r];
    float4 sv;
    sv.x = acc[r][0] + cw + qwS[c0 + 0] + bcq;
    sv.y = acc[r][1] + cw + qwS[c0 + 1] + bcq;
    sv.z = acc[r][2] + cw + qwS[c0 + 2] + bcq;
    sv.w = acc[r][3] + cw + qwS[c0 + 3] + bcq;
    *(float4*)&sS[(r0 + r) * 68 + c0] = sv;
  }
  __syncthreads();
  // ---- phase 2: rowmax + softmax over j (4 lanes per row) ----
  {
    int row = t >> 2, kk = t & 3;
    float sv[16];
#pragma unroll
    for (int u4 = 0; u4 < 4; ++u4) {
      float4 v = *(const float4*)&sS[row * 68 + kk * 16 + u4 * 4];
      sv[u4 * 4 + 0] = v.x; sv[u4 * 4 + 1] = v.y;
      sv[u4 * 4 + 2] = v.z; sv[u4 * 4 + 3] = v.w;
    }
    float mraw = NEGV, mm = NEGV, sm[16];
#pragma unroll
    for (int u = 0; u < 16; ++u) {
      int j = kk * 16 + u;
      mraw = fmaxf(mraw, sv[u]);
      sm[u] = (qmS[j] > 0.5f) ? sv[u] : NEGV;
      mm = fmaxf(mm, sm[u]);
    }
    mraw = fmaxf(mraw, __shfl_xor(mraw, 1));
    mraw = fmaxf(mraw, __shfl_xor(mraw, 2));
    mm = fmaxf(mm, __shfl_xor(mm, 1));
    mm = fmaxf(mm, __shfl_xor(mm, 2));
    if (kk == 0) rowmax[b * CL + i0 + row] = (cmS[row] > 0.5f) ? mraw : NEGV;
    float ps = 0.f, p[16];
#pragma unroll
    for (int u = 0; u < 16; ++u) { p[u] = __expf(sm[u] - mm); ps += p[u]; }
    ps += __shfl_xor(ps, 1);
    ps += __shfl_xor(ps, 2);
    float inv = 1.0f / ps;
#pragma unroll
    for (int u = 0; u < 16; ++u) aT[(kk * 16 + u) * 36 + row] = p[u] * inv;
  }
  // ---- phase 3: c2q = a @ q, write segs 0/1/2 ----
  const int ig2 = t >> 4, dg = t & 15;
  const int rr0 = ig2 * 4, dcol = dg * 8;
  for (int ch = 0; ch < NCH; ++ch) {
    const int d0 = ch * DC;
    __syncthreads();
#pragma unroll
    for (int s = 0; s < 16; ++s) {     // stage q chunk row-major [64][136]
      int f = t + s * 128, j = f >> 5, dd4 = f & 31;
      float4 v = *(const float4*)(q + qbase + (size_t)j * H + d0 + dd4 * 4);
      *(float4*)&qB[j * 136 + dd4 * 4] = v;
    }
    __syncthreads();
    float o[4][8] = {};
#pragma unroll 2
    for (int jb = 0; jb < 16; ++jb) {
#pragma unroll
      for (int k = 0; k < 4; ++k) {
        int j = jb * 4 + k;
        float4 av = *(const float4*)&aT[j * 36 + rr0];
        float4 q0 = *(const float4*)&qB[j * 136 + dcol];
        float4 q1 = *(const float4*)&qB[j * 136 + dcol + 4];
        float ar[4] = {av.x, av.y, av.z, av.w};
        float qv[8] = {q0.x, q0.y, q0.z, q0.w, q1.x, q1.y, q1.z, q1.w};
#pragma unroll
        for (int r = 0; r < 4; ++r)
#pragma unroll
          for (int e = 0; e < 8; ++e) o[r][e] += ar[r] * qv[e];
      }
    }
#pragma unroll
    for (int r = 0; r < 4; ++r) {
      size_t row = (size_t)b * CL + i0 + rr0 + r;
      const float* crow = c + row * H + d0 + dcol;
      float4 cv0 = *(const float4*)(crow);
      float4 cv1 = *(const float4*)(crow + 4);
      float* ob = out + row * OD + d0 + dcol;
      *(float4*)(ob) = cv0;
      *(float4*)(ob + 4) = cv1;
      float4 t0 = make_float4(o[r][0], o[r][1], o[r][2], o[r][3]);
      float4 t1 = make_float4(o[r][4], o[r][5], o[r][6], o[r][7]);
      *(float4*)(ob + H) = t0;
      *(float4*)(ob + H + 4) = t1;
      float4 m0 = make_float4(cv0.x * o[r][0], cv0.y * o[r][1],
                              cv0.z * o[r][2], cv0.w * o[r][3]);
      float4 m1 = make_float4(cv1.x * o[r][4], cv1.y * o[r][5],
                              cv1.z * o[r][6], cv1.w * o[r][7]);
      *(float4*)(ob + 2 * H) = m0;
      *(float4*)(ob + 2 * H + 4) = m1;
    }
  }
}

// ---------------- b_att = softmax_i(rowmax) ----------------
__global__ __launch_bounds__(256) void kb1(const float* __restrict__ rowmax,
                                           float* __restrict__ batt) {
  int b = blockIdx.x, t = threadIdx.x;
  __shared__ float red[4];
  float v0 = rowmax[b * CL + t], v1 = rowmax[b * CL + t + 256];
  float m = fmaxf(v0, v1);
#pragma unroll
  for (int off = 32; off; off >>= 1) m = fmaxf(m, __shfl_xor(m, off));
  if ((t & 63) == 0) red[t >> 6] = m;
  __syncthreads();
  m = fmaxf(fmaxf(red[0], red[1]), fmaxf(red[2], red[3]));
  float p0 = __expf(v0 - m), p1 = __expf(v1 - m);
  float s = p0 + p1;
#pragma unroll
  for (int off = 32; off; off >>= 1) s += __shfl_xor(s, off);
  __syncthreads();
  if ((t & 63) == 0) red[t >> 6] = s;
  __syncthreads();
  s = red[0] + red[1] + red[2] + red[3];
  float inv = 1.0f / s;
  batt[b * CL + t] = p0 * inv;
  batt[b * CL + t + 256] = p1 * inv;
}

// ---------------- q2c partials: 32 splits of 16 rows each ----------------
__global__ __launch_bounds__(256) void kb2(const float* __restrict__ c,
                                           const float* __restrict__ batt,
                                           float* __restrict__ part) {
  int s = blockIdx.x, b = blockIdx.y, t = threadIdx.x;
  __shared__ float ba[16];
  if (t < 16) ba[t] = batt[b * CL + s * 16 + t];
  __syncthreads();
  const float* cb = c + ((size_t)b * CL + s * 16) * H;
  float a0 = 0.f, a1 = 0.f, a2 = 0.f;
  for (int r = 0; r < 16; ++r) {
    float w = ba[r];
    const float* cr = cb + (size_t)r * H;
    a0 += w * cr[t]; a1 += w * cr[t + 256]; a2 += w * cr[t + 512];
  }
  float* pr = part + ((size_t)b * 32 + s) * H;
  pr[t] = a0; pr[t + 256] = a1; pr[t + 512] = a2;
}

// ---------------- q2c reduce ----------------
__global__ __launch_bounds__(256) void kb3(const float* __restrict__ part,
                                           float* __restrict__ q2c) {
  int b = blockIdx.x / 3, third = blockIdx.x % 3, t = threadIdx.x;
  int d = third * 256 + t;
  float s = 0.f;
  for (int k = 0; k < 32; ++k) s += part[((size_t)b * 32 + k) * H + d];
  q2c[b * H + d] = s;
}

// ---------------- out seg3 = c * q2c ----------------
__global__ __launch_bounds__(256) void kc(const float* __restrict__ c,
                                          const float* __restrict__ q2c,
                                          float* __restrict__ out) {
  const float4* c4 = (const float4*)c;
  const float4* g4 = (const float4*)q2c;
  float4* o4 = (float4*)out;
  int idx = blockIdx.x * 256 + threadIdx.x;
#pragma unroll
  for (int k = 0; k < 3; ++k, idx += 2048 * 256) {
    int row = idx / 192, dq = idx - row * 192;   // row = b*CL+i, dq = d/4
    int b = row >> 9;
    float4 cv = c4[(size_t)row * 192 + dq];
    float4 gv = g4[b * 192 + dq];
    float4 r;
    r.x = cv.x * gv.x; r.y = cv.y * gv.y; r.z = cv.z * gv.z; r.w = cv.w * gv.w;
    o4[(size_t)row * 768 + 576 + dq] = r;
  }
}

extern "C" void kernel_launch(void* const* d_in, const int* in_sizes, int n_in,
                              void* d_out, int out_size, void* d_ws, size_t ws_size,
                              hipStream_t stream) {
  const float* c      = (const float*)d_in[0];
  const float* q      = (const float*)d_in[1];
  const float* c_mask = (const float*)d_in[2];
  const float* q_mask = (const float*)d_in[3];
  const float* w_c    = (const float*)d_in[4];
  const float* b_c    = (const float*)d_in[5];
  const float* w_q    = (const float*)d_in[6];
  const float* b_q    = (const float*)d_in[7];
  const float* w_cq   = (const float*)d_in[8];
  const float* b_cq   = (const float*)d_in[9];
  float* out = (float*)d_out;
  float* ws  = (float*)d_ws;
  float* qw     = ws + WS_QW;
  float* rowmax = ws + WS_ROWMAX;
  float* batt   = ws + WS_BATT;
  float* part   = ws + WS_PART;
  float* q2c    = ws + WS_Q2C;

  k_qw<<<256, 256, 0, stream>>>(q, w_q, b_q, qw);
  ka<<<dim3(CL / IT, B_), 128, 0, stream>>>(c, q, c_mask, q_mask, w_c, b_c,
                                            w_cq, b_cq, qw, rowmax, out);
  kb1<<<B_, 256, 0, stream>>>(rowmax, batt);
  kb2<<<dim3(32, B_), 256, 0, stream>>>(c, batt, part);
  kb3<<<B_ * 3, 256, 0, stream>>>(part, q2c);
  kc<<<2048, 256, 0, stream>>>(c, q2c, out);
}